// Round 7
// baseline (162.415 us; speedup 1.0000x reference)
//
#include <hip/hip_runtime.h>
#include <hip/hip_bf16.h>
#include <math.h>

#define NN 262144
#define QQ 256
#define PS 80
#define BB 4096
#define NSLOT 4
#define BKI 32            // K per pipeline iteration
#define NITER 8           // QQ / BKI
#define ABYTES 16384      // A stage: 128 rows * 128 B (hi ch0-3 | lo ch4-7, XOR-swz)
#define STG 36864         // stage stride: A 16384 + B 20480 (160 cols * 128 B)
#define SMEM_BYTES 73728  // 2 stages; res union = 61440

typedef _Float16 f16x8 __attribute__((ext_vector_type(8)));
typedef float f32x4  __attribute__((ext_vector_type(4)));

__device__ inline unsigned short f16b(float f) {
  return __builtin_bit_cast(unsigned short, (_Float16)f);
}
__device__ inline float f16tof(unsigned short u) {
  return (float)__builtin_bit_cast(_Float16, u);
}

// ---------------------------------------------------------------------------
// Kernel 0: B = [beta_u | beta_z] -> fp16, TRANSPOSED [160][256].
// ---------------------------------------------------------------------------
__global__ void bsplit_k(const float* __restrict__ bu, const float* __restrict__ bz,
                         unsigned short* __restrict__ bT) {
  int c = blockIdx.x;     // 0..159
  int k = threadIdx.x;    // 0..255
  float v = (c < PS) ? bu[k * PS + c] : bz[k * PS + (c - PS)];
  bT[c * QQ + k] = f16b(v);
}

// ---------------------------------------------------------------------------
// Kernel 1: segment boundaries (seg_ids sorted, int32 from harness).
// ---------------------------------------------------------------------------
__global__ void seg_bounds_k(const int* __restrict__ seg, int* __restrict__ segstart) {
  int b = blockIdx.x * blockDim.x + threadIdx.x;
  if (b > BB) return;
  if (b == BB) { segstart[BB] = NN; return; }
  int lo = 0, hi = NN;
  while (lo < hi) {
    int mid = (lo + hi) >> 1;
    if (seg[mid] < b) lo = mid + 1; else hi = mid;
  }
  segstart[b] = lo;
}

// ---------------------------------------------------------------------------
// Kernel 2: FUSED [fp16 2-term MFMA GEMM 128x160x256] + [in-LDS segmented
// online softmax-pool partials]. 512 thr = 8 waves (4 row x 2 col-halves),
// wave tile 32r x 80c. Double-buffered staging, 1 barrier/iter, global loads
// issued one full iteration ahead (T14).
// A LDS row = 128 B, 8 chunks of 16B: hi k-group kg at chunk kg, lo at 4|kg,
// all XOR-swizzled ch^(row&7). Each thread stages 2 float4 (k=4qa, 16+4qa)
// -> full 32-k coverage (round-6 bug: only half was staged).
// B LDS col = 128 B, chunk kg^(col&7) (swizzle scatters 64B data over 128B).
// MFMA 16x16x32_f16: A row=lane&15, k=8*(lane>>4)+j; D col=lane&15,
// row=(lane>>4)*4+reg  [verified r3/r4].
// ---------------------------------------------------------------------------
__global__ __launch_bounds__(512, 4) void fused_k(
    const float* __restrict__ x, const unsigned short* __restrict__ bT,
    const int* __restrict__ seg, const int* __restrict__ segstart,
    float* __restrict__ pm, float* __restrict__ pse, float* __restrict__ pst) {
  __shared__ __align__(16) char smem[SMEM_BYTES];
  const int tid  = threadIdx.x;
  const int wid  = tid >> 6;
  const int lane = tid & 63;
  const int rs   = blockIdx.x * 128;

  const int wr   = (wid & 3) * 32;   // wave row offset
  const int cw   = wid >> 2;         // 0 -> u cols, 1 -> tz cols
  const int lrow = lane & 15;
  const int lk16 = lane >> 4;        // 0..3 == kg of the frag

  // staging mapping
  const int ra  = tid >> 2;          // A row 0..127
  const int qa  = tid & 3;           // float4 slot; covers k=4qa and k=16+4qa
  const int cb0 = tid >> 2;          // B col set 0: 0..127
  const int kg0 = tid & 3;
  const int cb1 = 128 + (tid >> 2);  // B col set 1 (tid<128): 128..159
  const int kg1 = tid & 3;

  const float* xp = x + (size_t)(rs + ra) * QQ + qa * 4;
  const unsigned short* bp0 = bT + cb0 * QQ + kg0 * 8;
  const unsigned short* bp1 = bT + cb1 * QQ + kg1 * 8;

  float4 xr[2][2]; uint4 br0[2], br1[2];

#define LOADI(s_, t_) do {                                                   \
    xr[s_][0] = *reinterpret_cast<const float4*>(xp + (t_) * BKI);           \
    xr[s_][1] = *reinterpret_cast<const float4*>(xp + (t_) * BKI + 16);      \
    br0[s_] = *reinterpret_cast<const uint4*>(bp0 + (t_) * BKI);             \
    if (tid < 128) br1[s_] = *reinterpret_cast<const uint4*>(bp1 + (t_) * BKI); \
  } while (0)

#define SPLIT4(v, hw, lw) do {                                               \
    unsigned short h0 = f16b((v).x), h1 = f16b((v).y);                       \
    unsigned short h2 = f16b((v).z), h3 = f16b((v).w);                       \
    unsigned short l0 = f16b((v).x - f16tof(h0)), l1 = f16b((v).y - f16tof(h1)); \
    unsigned short l2 = f16b((v).z - f16tof(h2)), l3 = f16b((v).w - f16tof(h3)); \
    hw = make_uint2((unsigned)h0 | ((unsigned)h1 << 16),                     \
                    (unsigned)h2 | ((unsigned)h3 << 16));                    \
    lw = make_uint2((unsigned)l0 | ((unsigned)l1 << 16),                     \
                    (unsigned)l2 | ((unsigned)l3 << 16));                    \
  } while (0)

#define WRITEI(s_, b_) do {                                                  \
    char* A_ = smem + (b_) * STG;                                            \
    char* B_ = A_ + ABYTES;                                                  \
    uint2 hw0, lw0, hw1, lw1;                                                \
    SPLIT4(xr[s_][0], hw0, lw0);                                             \
    SPLIT4(xr[s_][1], hw1, lw1);                                             \
    int swz  = ra & 7;                                                       \
    int off8 = (qa & 1) * 8;                                                 \
    char* Ar = A_ + ra * 128;                                                \
    *reinterpret_cast<uint2*>(Ar + (((qa >> 1)       ^ swz) * 16) + off8) = hw0; \
    *reinterpret_cast<uint2*>(Ar + (((4 | (qa >> 1)) ^ swz) * 16) + off8) = lw0; \
    *reinterpret_cast<uint2*>(Ar + (((2 + (qa >> 1)) ^ swz) * 16) + off8) = hw1; \
    *reinterpret_cast<uint2*>(Ar + (((6 + (qa >> 1)) ^ swz) * 16) + off8) = lw1; \
    *reinterpret_cast<uint4*>(B_ + cb0 * 128 + ((kg0 ^ (cb0 & 7)) * 16)) = br0[s_]; \
    if (tid < 128)                                                           \
      *reinterpret_cast<uint4*>(B_ + cb1 * 128 + ((kg1 ^ (cb1 & 7)) * 16)) = br1[s_]; \
  } while (0)

  f32x4 acc[2][5];
#pragma unroll
  for (int m = 0; m < 2; ++m)
#pragma unroll
    for (int n = 0; n < 5; ++n) acc[m][n] = (f32x4){0.f, 0.f, 0.f, 0.f};

  // prologue: k-tile 0 staged, k-tile 1 in flight
  LOADI(0, 0);
  WRITEI(0, 0);
  LOADI(1, 1);
  __syncthreads();

#pragma unroll
  for (int t = 0; t < NITER; ++t) {
    const char* A_ = smem + (t & 1) * STG;
    const char* B_ = A_ + ABYTES;
    f16x8 ah[2], al[2], bf[5];
#pragma unroll
    for (int m = 0; m < 2; ++m) {
      int r = wr + m * 16 + lrow;
      const char* rp = A_ + r * 128;
      ah[m] = *reinterpret_cast<const f16x8*>(rp + ((lk16 ^ (r & 7)) * 16));
      al[m] = *reinterpret_cast<const f16x8*>(rp + (((4 | lk16) ^ (r & 7)) * 16));
    }
#pragma unroll
    for (int n = 0; n < 5; ++n) {
      int c = cw * 80 + n * 16 + lrow;
      bf[n] = *reinterpret_cast<const f16x8*>(B_ + c * 128 + ((lk16 ^ (c & 7)) * 16));
    }
    __builtin_amdgcn_s_setprio(1);
#pragma unroll
    for (int n = 0; n < 5; ++n)
#pragma unroll
      for (int m = 0; m < 2; ++m) {
        acc[m][n] = __builtin_amdgcn_mfma_f32_16x16x32_f16(ah[m], bf[n], acc[m][n], 0, 0, 0);
        acc[m][n] = __builtin_amdgcn_mfma_f32_16x16x32_f16(al[m], bf[n], acc[m][n], 0, 0, 0);
      }
    __builtin_amdgcn_s_setprio(0);
    if (t < NITER - 1) {
      WRITEI((t + 1) & 1, (t + 1) & 1);        // k-tile t+1 -> other buffer
      if (t < NITER - 2) LOADI(t & 1, t + 2);  // k-tile t+2 in flight
    }
    __syncthreads();
  }
#undef LOADI
#undef WRITEI
#undef SPLIT4

  // ---- result tile to LDS (u as f32, t as fp16); overwrites staging
  float* res_u          = reinterpret_cast<float*>(smem);                  // 40960
  unsigned short* res_v = reinterpret_cast<unsigned short*>(smem + 40960); // 20480
#pragma unroll
  for (int m = 0; m < 2; ++m)
#pragma unroll
    for (int n = 0; n < 5; ++n)
#pragma unroll
      for (int r = 0; r < 4; ++r) {
        int row = wr + m * 16 + lk16 * 4 + r;
        int col = n * 16 + lrow;
        if (cw == 0) res_u[row * 80 + col] = acc[m][n][r];
        else         res_v[row * 80 + col] = f16b(acc[m][n][r]);
      }
  __syncthreads();

  // ---- segmented online softmax-pool over this 128-row strip
  int b0 = seg[rs];
  int b1 = seg[rs + 127];
  int nu = (b1 - b0 + 1) * PS;
  for (int u = tid; u < nu; u += 512) {
    int bag = b0 + u / PS;
    int c   = u % PS;
    int sb  = segstart[bag];
    int lo  = max(sb, rs) - rs;
    int hi  = min(segstart[bag + 1], rs + 128) - rs;
    float m_ = -3.4e38f, se = 0.f, st = 0.f;
    for (int r = lo; r < hi; ++r) {
      float v  = res_u[r * 80 + c];
      float tv = f16tof(res_v[r * 80 + c]);
      float nm = fmaxf(m_, v);
      float sc = __expf(m_ - nm);
      float ee = __expf(v - nm);
      se = se * sc + ee;
      st = st * sc + ee * tv;
      m_ = nm;
    }
    int slot = blockIdx.x - (sb >> 7);   // 0..nstrips-1 for this bag
    size_t p = ((size_t)bag * NSLOT + slot) * PS + c;
    pm[p] = m_; pse[p] = se; pst[p] = st;
  }
}

// ---------------------------------------------------------------------------
// Kernel 3: merge partial slots per (bag,col) -> zb (= d_out). Exact slot
// count derived from segstart (no sentinels / no init pass).
// ---------------------------------------------------------------------------
__global__ __launch_bounds__(256) void combine_k(
    const int* __restrict__ segstart,
    const float* __restrict__ pm, const float* __restrict__ pse,
    const float* __restrict__ pst, float* __restrict__ zb) {
  int i = blockIdx.x * 256 + threadIdx.x;   // BB*PS
  if (i >= BB * PS) return;
  int bag = i / PS, c = i % PS;
  int sb = segstart[bag], eb = segstart[bag + 1];
  float z = 0.f;
  if (eb > sb) {
    int ns = ((eb - 1) >> 7) - (sb >> 7) + 1;
    ns = min(ns, NSLOT);
    float m = -3.4e38f, se = 0.f, st = 0.f;
    for (int s = 0; s < ns; ++s) {
      size_t p = ((size_t)bag * NSLOT + s) * PS + c;
      float m2 = pm[p], se2 = pse[p], st2 = pst[p];
      float nm = fmaxf(m, m2);
      float s1 = __expf(m - nm);
      float s2 = __expf(m2 - nm);
      se = se * s1 + se2 * s2;
      st = st * s1 + st2 * s2;
      m = nm;
    }
    z = st / se;
  }
  zb[i] = z;
}

// ---------------------------------------------------------------------------
// Kernel 4: per-column stats + b-scale, IN PLACE on d_out.
// ---------------------------------------------------------------------------
__device__ inline float wave_sum(float v) {
#pragma unroll
  for (int o = 32; o > 0; o >>= 1) v += __shfl_down(v, o, 64);
  return v;
}

__global__ __launch_bounds__(256) void finalize_k(
    const float* __restrict__ bz, float* __restrict__ zb_out) {
  const int c = blockIdx.x;
  const int t = threadIdx.x;

  float bvz = bz[t * PS + c];
  float bsq = bvz * bvz;

  float s = 0.f, ss = 0.f;
  for (int b = t; b < BB; b += 256) {
    float z = zb_out[b * PS + c];
    s += z;
    ss += z * z;
  }

  __shared__ float w0[4], w1[4], w2[4];
  float a0 = wave_sum(bsq);
  float a1 = wave_sum(s);
  float a2 = wave_sum(ss);
  int wid = t >> 6, lane = t & 63;
  if (lane == 0) { w0[wid] = a0; w1[wid] = a1; w2[wid] = a2; }
  __syncthreads();

  __shared__ float sh[3];
  if (t == 0) {
    float B0 = w0[0] + w0[1] + w0[2] + w0[3];
    float S1 = w1[0] + w1[1] + w1[2] + w1[3];
    float S2 = w2[0] + w2[1] + w2[2] + w2[3];
    float bval = sqrtf(B0 / (float)QQ);
    float mean = S1 / (float)BB;
    float var = (S2 - (float)BB * mean * mean) / (float)(BB - 1);
    float sd = sqrtf(fmaxf(var, 0.f));
    if (!(sd > 0.f) || sd != sd) sd = 1.f;
    sh[0] = bval; sh[1] = mean; sh[2] = sd;
  }
  __syncthreads();
  float bval = sh[0], mean = sh[1], sd = sh[2];
  for (int b = t; b < BB; b += 256) {
    zb_out[b * PS + c] = bval * (zb_out[b * PS + c] - mean) / sd;
  }
}

// ---------------------------------------------------------------------------
extern "C" void kernel_launch(void* const* d_in, const int* in_sizes, int n_in,
                              void* d_out, int out_size, void* d_ws, size_t ws_size,
                              hipStream_t stream) {
  const float* x   = (const float*)d_in[0];
  const float* bu  = (const float*)d_in[1];
  const float* bz  = (const float*)d_in[2];
  const int*   seg = (const int*)d_in[3];   // harness narrows int64 -> int32
  float* out = (float*)d_out;

  // workspace layout (bytes):
  //   [0,     16640)  segstart (4097 ints, padded)
  //   [16640, 98560)  bT: 160*256 fp16
  //   [98560, ...)    pm / pse / pst: BB*NSLOT*PS floats each
  char* ws = (char*)d_ws;
  int* segstart      = (int*)ws;
  unsigned short* bT = (unsigned short*)(ws + 16640);
  size_t pn  = (size_t)BB * NSLOT * PS;
  float* pm  = (float*)(ws + 98560);
  float* pse = pm + pn;
  float* pst = pse + pn;

  bsplit_k<<<160, QQ, 0, stream>>>(bu, bz, bT);
  seg_bounds_k<<<(BB + 1 + 255) / 256, 256, 0, stream>>>(seg, segstart);
  fused_k<<<NN / 128, 512, 0, stream>>>(x, bT, seg, segstart, pm, pse, pst);
  combine_k<<<(BB * PS + 255) / 256, 256, 0, stream>>>(segstart, pm, pse, pst, out);
  finalize_k<<<PS, 256, 0, stream>>>(bz, out);
}

// Round 8
// 119.495 us; speedup vs baseline: 1.3592x; 1.3592x over previous
//
#include <hip/hip_runtime.h>
#include <hip/hip_bf16.h>
#include <math.h>

#define NN 262144
#define QQ 256
#define PS 80
#define BB 4096
#define NSLOT 4
#define RT 64             // rows per strip
#define NITER 8           // K tiles of 32
#define A_BYTES 8192      // [4 kg][2 hl][64 rowswz][16B]
#define B_BYTES 10240     // [4 kg][160 cswz][16B]
#define STG 18432         // A_BYTES + B_BYTES
#define SMEM_BYTES 36864  // 2 stages; res union = 30720

typedef _Float16 f16x8 __attribute__((ext_vector_type(8)));
typedef float f32x4  __attribute__((ext_vector_type(4)));
typedef const __attribute__((address_space(1))) unsigned int g_u32;
typedef __attribute__((address_space(3))) unsigned int l_u32;

__device__ inline unsigned short f16b(float f) {
  return __builtin_bit_cast(unsigned short, (_Float16)f);
}
__device__ inline float f16tof(unsigned short u) {
  return (float)__builtin_bit_cast(_Float16, u);
}

// ---------------------------------------------------------------------------
// Kernel 0: pre-swizzled fp16 B in the exact per-K-tile LDS image:
// bSwz[kt][kg][c ^ (kg<<2)][8 fp16]  (kt<8, kg<4, c<160)
// so fused_k can global_load_lds it linearly (16B/lane).
// ---------------------------------------------------------------------------
__global__ void bprep_k(const float* __restrict__ bu, const float* __restrict__ bz,
                        unsigned short* __restrict__ bSwz) {
  int gid = blockIdx.x * 256 + threadIdx.x;   // 8*4*160 = 5120 units
  if (gid >= 5120) return;
  int kt  = gid / 640;
  int rem = gid - kt * 640;
  int kg  = rem / 160;
  int c   = rem - kg * 160;
  int csw = c ^ (kg << 2);                    // low-4-bit XOR, stays in [0,160)
  unsigned short* dst = bSwz + (size_t)kt * 5120 + kg * 1280 + csw * 8;
  int kbase = kt * 32 + kg * 8;
#pragma unroll
  for (int j = 0; j < 8; ++j) {
    int k = kbase + j;
    float v = (c < PS) ? bu[k * PS + c] : bz[k * PS + (c - PS)];
    dst[j] = f16b(v);
  }
}

// ---------------------------------------------------------------------------
// Kernel 1: segment boundaries (seg_ids sorted, int32 from harness).
// ---------------------------------------------------------------------------
__global__ void seg_bounds_k(const int* __restrict__ seg, int* __restrict__ segstart) {
  int b = blockIdx.x * blockDim.x + threadIdx.x;
  if (b > BB) return;
  if (b == BB) { segstart[BB] = NN; return; }
  int lo = 0, hi = NN;
  while (lo < hi) {
    int mid = (lo + hi) >> 1;
    if (seg[mid] < b) lo = mid + 1; else hi = mid;
  }
  segstart[b] = lo;
}

// ---------------------------------------------------------------------------
// Kernel 2: FUSED fp16 2-term MFMA GEMM (64x160x256 per block) + in-LDS
// segmented online softmax-pool. 512 thr = 8 waves (4 row-waves x 16 rows,
// 2 col-halves x 80 cols). 4 blocks/CU target: LDS 36.9KB, regs capped 64.
// A: reg-staged (f32->f16 hi/lo split in-flight), 2-deep prefetch.
// B: global_load_lds direct from pre-swizzled bSwz (no reg round-trip).
// LDS layouts (conflict-free reads; <=2-way writes):
//   A chunk addr = kg*2048 + hl*1024 + (row ^ (kg<<2))*16 (+8B half)
//   B chunk addr = kg*2560 + (c ^ (kg<<2))*16
// MFMA 16x16x32_f16: A row=lane&15, k=8*(lane>>4)+j; D col=lane&15,
// row=(lane>>4)*4+reg  [verified r3-r7].
// ---------------------------------------------------------------------------
__global__ __launch_bounds__(512, 8) void fused_k(
    const float* __restrict__ x, const unsigned short* __restrict__ bSwz,
    const int* __restrict__ seg, const int* __restrict__ segstart,
    float* __restrict__ pm, float* __restrict__ pse, float* __restrict__ pst) {
  __shared__ __align__(16) char smem[SMEM_BYTES];
  const int tid  = threadIdx.x;
  const int wid  = tid >> 6;
  const int lane = tid & 63;
  const int rs   = blockIdx.x * RT;

  const int wr   = (wid & 3) * 16;   // wave row offset
  const int cw   = wid >> 2;         // 0 -> u cols, 1 -> tz cols
  const int lrow = lane & 15;
  const int lk16 = lane >> 4;

  // A staging mapping: one float4 (16 k-floats? no: 4 floats, k=4qa..4qa+3)
  const int ra = tid >> 3;           // row 0..63
  const int qa = tid & 7;            // k = 4*qa
  const float* xp = x + (size_t)(rs + ra) * QQ + qa * 4;

  float4 xr[2];

  // B: 10 KB per tile = 10 wave-segments of 1024B; wave w does seg w (+ w+8 if w<2)
#define BGLOAD(kt_, b_) do {                                                  \
    char* dstb = smem + (b_) * STG + A_BYTES;                                 \
    const char* srcb = (const char*)bSwz + (size_t)(kt_) * B_BYTES;           \
    __builtin_amdgcn_global_load_lds(                                         \
        (g_u32*)(srcb + wid * 1024 + lane * 16),                              \
        (l_u32*)(dstb + wid * 1024), 16, 0, 0);                               \
    if (wid < 2)                                                              \
      __builtin_amdgcn_global_load_lds(                                       \
          (g_u32*)(srcb + 8192 + wid * 1024 + lane * 16),                     \
          (l_u32*)(dstb + 8192 + wid * 1024), 16, 0, 0);                      \
  } while (0)

#define LOADI(s_, t_) do { xr[s_] = *reinterpret_cast<const float4*>(xp + (t_) * 32); } while (0)

#define WRITEI(s_, b_) do {                                                   \
    char* A_ = smem + (b_) * STG;                                             \
    float4 v = xr[s_];                                                        \
    unsigned short h0 = f16b(v.x), h1 = f16b(v.y), h2 = f16b(v.z), h3 = f16b(v.w); \
    unsigned short l0 = f16b(v.x - f16tof(h0)), l1 = f16b(v.y - f16tof(h1));  \
    unsigned short l2 = f16b(v.z - f16tof(h2)), l3 = f16b(v.w - f16tof(h3));  \
    uint2 hw = make_uint2((unsigned)h0 | ((unsigned)h1 << 16),                \
                          (unsigned)h2 | ((unsigned)h3 << 16));               \
    uint2 lw = make_uint2((unsigned)l0 | ((unsigned)l1 << 16),                \
                          (unsigned)l2 | ((unsigned)l3 << 16));               \
    int kg  = qa >> 1;                                                        \
    int rof = (ra ^ (kg << 2)) * 16 + (qa & 1) * 8;                           \
    *reinterpret_cast<uint2*>(A_ + kg * 2048 + rof) = hw;                     \
    *reinterpret_cast<uint2*>(A_ + kg * 2048 + 1024 + rof) = lw;              \
  } while (0)

  f32x4 acc[5];
#pragma unroll
  for (int n = 0; n < 5; ++n) acc[n] = (f32x4){0.f, 0.f, 0.f, 0.f};

  // prologue
  LOADI(0, 0);
  BGLOAD(0, 0);
  WRITEI(0, 0);
  LOADI(1, 1);
  __syncthreads();   // drains BGLOAD(0) + A writes

#pragma unroll
  for (int t = 0; t < NITER; ++t) {
    if (t < NITER - 1) BGLOAD(t + 1, (t + 1) & 1);
    if (t < NITER - 2) LOADI(t & 1, t + 2);

    const char* A_ = smem + (t & 1) * STG;
    const char* B_ = A_ + A_BYTES;
    int r    = wr + lrow;
    int arof = (r ^ (lk16 << 2)) * 16;
    f16x8 ah = *reinterpret_cast<const f16x8*>(A_ + lk16 * 2048 + arof);
    f16x8 al = *reinterpret_cast<const f16x8*>(A_ + lk16 * 2048 + 1024 + arof);
    __builtin_amdgcn_s_setprio(1);
#pragma unroll
    for (int n = 0; n < 5; ++n) {
      int c = cw * 80 + n * 16 + lrow;
      f16x8 bf = *reinterpret_cast<const f16x8*>(B_ + lk16 * 2560 + ((c ^ (lk16 << 2)) * 16));
      acc[n] = __builtin_amdgcn_mfma_f32_16x16x32_f16(ah, bf, acc[n], 0, 0, 0);
      acc[n] = __builtin_amdgcn_mfma_f32_16x16x32_f16(al, bf, acc[n], 0, 0, 0);
    }
    __builtin_amdgcn_s_setprio(0);

    if (t < NITER - 1) WRITEI((t + 1) & 1, (t + 1) & 1);
    __syncthreads();
  }
#undef BGLOAD
#undef LOADI
#undef WRITEI

  // ---- result tile to LDS (u f32, t fp16); overwrites staging (post-barrier)
  float* res_u          = reinterpret_cast<float*>(smem);                  // 20480
  unsigned short* res_v = reinterpret_cast<unsigned short*>(smem + 20480); // 10240
#pragma unroll
  for (int n = 0; n < 5; ++n)
#pragma unroll
    for (int rr = 0; rr < 4; ++rr) {
      int row = wr + lk16 * 4 + rr;
      int col = n * 16 + lrow;
      if (cw == 0) res_u[row * 80 + col] = acc[n][rr];
      else         res_v[row * 80 + col] = f16b(acc[n][rr]);
    }
  __syncthreads();

  // ---- segmented online softmax-pool over this 64-row strip
  int b0 = seg[rs];
  int b1 = seg[rs + RT - 1];
  int nu = (b1 - b0 + 1) * PS;
  for (int u = tid; u < nu; u += 512) {
    int bag = b0 + u / PS;
    int c   = u % PS;
    int sb  = segstart[bag];
    int lo  = max(sb, rs) - rs;
    int hi  = min(segstart[bag + 1], rs + RT) - rs;
    float m_ = -3.4e38f, se = 0.f, st = 0.f;
    for (int r = lo; r < hi; ++r) {
      float v  = res_u[r * 80 + c];
      float tv = f16tof(res_v[r * 80 + c]);
      float nm = fmaxf(m_, v);
      float sc = __expf(m_ - nm);
      float ee = __expf(v - nm);
      se = se * sc + ee;
      st = st * sc + ee * tv;
      m_ = nm;
    }
    int slot = blockIdx.x - (sb >> 6);
    size_t p = ((size_t)bag * NSLOT + slot) * PS + c;
    pm[p] = m_; pse[p] = se; pst[p] = st;
  }
}

// ---------------------------------------------------------------------------
// Kernel 3: merge partial slots per (bag,col) -> zb (= d_out).
// ---------------------------------------------------------------------------
__global__ __launch_bounds__(256) void combine_k(
    const int* __restrict__ segstart,
    const float* __restrict__ pm, const float* __restrict__ pse,
    const float* __restrict__ pst, float* __restrict__ zb) {
  int i = blockIdx.x * 256 + threadIdx.x;   // BB*PS
  if (i >= BB * PS) return;
  int bag = i / PS, c = i % PS;
  int sb = segstart[bag], eb = segstart[bag + 1];
  float z = 0.f;
  if (eb > sb) {
    int ns = ((eb - 1) >> 6) - (sb >> 6) + 1;
    ns = min(ns, NSLOT);
    float m = -3.4e38f, se = 0.f, st = 0.f;
    for (int s = 0; s < ns; ++s) {
      size_t p = ((size_t)bag * NSLOT + s) * PS + c;
      float m2 = pm[p], se2 = pse[p], st2 = pst[p];
      float nm = fmaxf(m, m2);
      float s1 = __expf(m - nm);
      float s2 = __expf(m2 - nm);
      se = se * s1 + se2 * s2;
      st = st * s1 + st2 * s2;
      m = nm;
    }
    z = st / se;
  }
  zb[i] = z;
}

// ---------------------------------------------------------------------------
// Kernel 4: per-column stats + b-scale, IN PLACE on d_out.
// ---------------------------------------------------------------------------
__device__ inline float wave_sum(float v) {
#pragma unroll
  for (int o = 32; o > 0; o >>= 1) v += __shfl_down(v, o, 64);
  return v;
}

__global__ __launch_bounds__(256) void finalize_k(
    const float* __restrict__ bz, float* __restrict__ zb_out) {
  const int c = blockIdx.x;
  const int t = threadIdx.x;

  float bvz = bz[t * PS + c];
  float bsq = bvz * bvz;

  float s = 0.f, ss = 0.f;
  for (int b = t; b < BB; b += 256) {
    float z = zb_out[b * PS + c];
    s += z;
    ss += z * z;
  }

  __shared__ float w0[4], w1[4], w2[4];
  float a0 = wave_sum(bsq);
  float a1 = wave_sum(s);
  float a2 = wave_sum(ss);
  int wid = t >> 6, lane = t & 63;
  if (lane == 0) { w0[wid] = a0; w1[wid] = a1; w2[wid] = a2; }
  __syncthreads();

  __shared__ float sh[3];
  if (t == 0) {
    float B0 = w0[0] + w0[1] + w0[2] + w0[3];
    float S1 = w1[0] + w1[1] + w1[2] + w1[3];
    float S2 = w2[0] + w2[1] + w2[2] + w2[3];
    float bval = sqrtf(B0 / (float)QQ);
    float mean = S1 / (float)BB;
    float var = (S2 - (float)BB * mean * mean) / (float)(BB - 1);
    float sd = sqrtf(fmaxf(var, 0.f));
    if (!(sd > 0.f) || sd != sd) sd = 1.f;
    sh[0] = bval; sh[1] = mean; sh[2] = sd;
  }
  __syncthreads();
  float bval = sh[0], mean = sh[1], sd = sh[2];
  for (int b = t; b < BB; b += 256) {
    zb_out[b * PS + c] = bval * (zb_out[b * PS + c] - mean) / sd;
  }
}

// ---------------------------------------------------------------------------
extern "C" void kernel_launch(void* const* d_in, const int* in_sizes, int n_in,
                              void* d_out, int out_size, void* d_ws, size_t ws_size,
                              hipStream_t stream) {
  const float* x   = (const float*)d_in[0];
  const float* bu  = (const float*)d_in[1];
  const float* bz  = (const float*)d_in[2];
  const int*   seg = (const int*)d_in[3];   // harness narrows int64 -> int32
  float* out = (float*)d_out;

  // workspace layout (bytes):
  //   [0,     16640)  segstart (4097 ints, padded)
  //   [16640, 98560)  bSwz: 8*4*160*8 fp16 = 81920
  //   [98560, ...)    pm / pse / pst: BB*NSLOT*PS floats each
  char* ws = (char*)d_ws;
  int* segstart        = (int*)ws;
  unsigned short* bSwz = (unsigned short*)(ws + 16640);
  size_t pn  = (size_t)BB * NSLOT * PS;
  float* pm  = (float*)(ws + 98560);
  float* pse = pm + pn;
  float* pst = pse + pn;

  bprep_k<<<20, 256, 0, stream>>>(bu, bz, bSwz);
  seg_bounds_k<<<(BB + 1 + 255) / 256, 256, 0, stream>>>(seg, segstart);
  fused_k<<<NN / RT, 512, 0, stream>>>(x, bSwz, seg, segstart, pm, pse, pst);
  combine_k<<<(BB * PS + 255) / 256, 256, 0, stream>>>(segstart, pm, pse, pst, out);
  finalize_k<<<PS, 256, 0, stream>>>(bz, out);
}

// Round 9
// 104.993 us; speedup vs baseline: 1.5469x; 1.1381x over previous
//
#include <hip/hip_runtime.h>
#include <hip/hip_bf16.h>
#include <math.h>

#define NN 262144
#define QQ 256
#define PS 80
#define BB 4096
#define NSLOT 4
#define RT 64             // rows per strip
#define NITER 8           // K tiles of 32
#define A_BYTES 4096      // [4 kg][64 row^swz][16B]  (fp16, 1 term)
#define B_BYTES 10240     // [4 kg][160 c^swz][16B]
#define STG 14336         // A_BYTES + B_BYTES
#define SMEM_BYTES 30720  // res union (30720) > 2 stages (28672)

typedef _Float16 f16x8 __attribute__((ext_vector_type(8)));
typedef float f32x4  __attribute__((ext_vector_type(4)));
typedef const __attribute__((address_space(1))) unsigned int g_u32;
typedef __attribute__((address_space(3))) unsigned int l_u32;

__device__ inline unsigned short f16b(float f) {
  return __builtin_bit_cast(unsigned short, (_Float16)f);
}
__device__ inline float f16tof(unsigned short u) {
  return (float)__builtin_bit_cast(_Float16, u);
}

// ---------------------------------------------------------------------------
// Kernel 0: pre-swizzled fp16 B in the exact per-K-tile LDS image:
// bSwz[kt][kg][c ^ (kg<<2)][8 fp16]  (kt<8, kg<4, c<160)  [validated r8]
// ---------------------------------------------------------------------------
__global__ void bprep_k(const float* __restrict__ bu, const float* __restrict__ bz,
                        unsigned short* __restrict__ bSwz) {
  int gid = blockIdx.x * 256 + threadIdx.x;   // 8*4*160 = 5120 units
  if (gid >= 5120) return;
  int kt  = gid / 640;
  int rem = gid - kt * 640;
  int kg  = rem / 160;
  int c   = rem - kg * 160;
  int csw = c ^ (kg << 2);
  unsigned short* dst = bSwz + (size_t)kt * 5120 + kg * 1280 + csw * 8;
  int kbase = kt * 32 + kg * 8;
#pragma unroll
  for (int j = 0; j < 8; ++j) {
    int k = kbase + j;
    float v = (c < PS) ? bu[k * PS + c] : bz[k * PS + (c - PS)];
    dst[j] = f16b(v);
  }
}

// ---------------------------------------------------------------------------
// Kernel 1: segment boundaries (seg_ids sorted, int32 from harness).
// ---------------------------------------------------------------------------
__global__ void seg_bounds_k(const int* __restrict__ seg, int* __restrict__ segstart) {
  int b = blockIdx.x * blockDim.x + threadIdx.x;
  if (b > BB) return;
  if (b == BB) { segstart[BB] = NN; return; }
  int lo = 0, hi = NN;
  while (lo < hi) {
    int mid = (lo + hi) >> 1;
    if (seg[mid] < b) lo = mid + 1; else hi = mid;
  }
  segstart[b] = lo;
}

// ---------------------------------------------------------------------------
// Kernel 2: FUSED fp16 1-term MFMA GEMM (64x160x256 per block) + in-LDS
// segmented online softmax-pool. 256 thr = 4 waves (2 row x 2 col), wave
// tile 32r x 80c (acc 2x5). 4 blocks/CU (LDS 30.7KB, VGPR capped 128).
// A: reg-staged f32->fp16, one uint4 ds_write per thread per iter.
// B: global_load_lds direct from pre-swizzled bSwz.
// LDS (16B chunks, contiguous 256B per 16 lanes -> conflict-free):
//   A addr = kg*1024 + (row ^ (kg<<2))*16
//   B addr = kg*2560 + (c   ^ (kg<<2))*16
// MFMA 16x16x32_f16: A row=lane&15, k=8*(lane>>4)+j; D col=lane&15,
// row=(lane>>4)*4+reg  [verified r3-r8].
// ---------------------------------------------------------------------------
__global__ __launch_bounds__(256, 4) void fused_k(
    const float* __restrict__ x, const unsigned short* __restrict__ bSwz,
    const int* __restrict__ seg, const int* __restrict__ segstart,
    float* __restrict__ pm, float* __restrict__ pse, float* __restrict__ pst) {
  __shared__ __align__(16) char smem[SMEM_BYTES];
  const int tid  = threadIdx.x;
  const int wid  = tid >> 6;
  const int lane = tid & 63;
  const int rs   = blockIdx.x * RT;

  const int wr   = (wid & 1) * 32;   // wave row offset
  const int cw   = wid >> 1;         // 0 -> u cols, 1 -> tz cols
  const int lrow = lane & 15;
  const int lk16 = lane >> 4;

  // A staging map: thread -> (row ra, k-group kg), 8 fp16 per iter
  const int ra = tid >> 2;           // 0..63
  const int kg = tid & 3;            // k = 8*kg within tile
  const float* xp = x + (size_t)(rs + ra) * QQ + kg * 8;

  float4 xr[2][2];

#define BGLOAD(kt_, b_) do {                                                  \
    char* dstb = smem + (b_) * STG + A_BYTES;                                 \
    const char* srcb = (const char*)bSwz + (size_t)(kt_) * B_BYTES;           \
    __builtin_amdgcn_global_load_lds(                                         \
        (g_u32*)(srcb + wid * 1024 + lane * 16),                              \
        (l_u32*)(dstb + wid * 1024), 16, 0, 0);                               \
    __builtin_amdgcn_global_load_lds(                                         \
        (g_u32*)(srcb + 4096 + wid * 1024 + lane * 16),                       \
        (l_u32*)(dstb + 4096 + wid * 1024), 16, 0, 0);                        \
    if (wid < 2)                                                              \
      __builtin_amdgcn_global_load_lds(                                       \
          (g_u32*)(srcb + 8192 + wid * 1024 + lane * 16),                     \
          (l_u32*)(dstb + 8192 + wid * 1024), 16, 0, 0);                      \
  } while (0)

#define LOADI(s_, t_) do {                                                    \
    xr[s_][0] = *reinterpret_cast<const float4*>(xp + (t_) * 32);             \
    xr[s_][1] = *reinterpret_cast<const float4*>(xp + (t_) * 32 + 4);         \
  } while (0)

#define WRITEI(s_, b_) do {                                                   \
    float4 v0 = xr[s_][0], v1 = xr[s_][1];                                    \
    unsigned short a0 = f16b(v0.x), a1 = f16b(v0.y), a2 = f16b(v0.z), a3 = f16b(v0.w); \
    unsigned short a4 = f16b(v1.x), a5 = f16b(v1.y), a6 = f16b(v1.z), a7 = f16b(v1.w); \
    uint4 w = make_uint4((unsigned)a0 | ((unsigned)a1 << 16),                 \
                         (unsigned)a2 | ((unsigned)a3 << 16),                 \
                         (unsigned)a4 | ((unsigned)a5 << 16),                 \
                         (unsigned)a6 | ((unsigned)a7 << 16));                \
    *reinterpret_cast<uint4*>(smem + (b_) * STG + kg * 1024 +                 \
                              ((ra ^ (kg << 2)) * 16)) = w;                   \
  } while (0)

  f32x4 acc[2][5];
#pragma unroll
  for (int m = 0; m < 2; ++m)
#pragma unroll
    for (int n = 0; n < 5; ++n) acc[m][n] = (f32x4){0.f, 0.f, 0.f, 0.f};

  // prologue
  LOADI(0, 0);
  BGLOAD(0, 0);
  WRITEI(0, 0);
  LOADI(1, 1);
  __syncthreads();

#pragma unroll
  for (int t = 0; t < NITER; ++t) {
    if (t < NITER - 1) BGLOAD(t + 1, (t + 1) & 1);
    if (t < NITER - 2) LOADI(t & 1, t + 2);

    const char* A_ = smem + (t & 1) * STG;
    const char* B_ = A_ + A_BYTES;
    f16x8 ah[2];
#pragma unroll
    for (int m = 0; m < 2; ++m) {
      int r = wr + m * 16 + lrow;
      ah[m] = *reinterpret_cast<const f16x8*>(A_ + lk16 * 1024 + ((r ^ (lk16 << 2)) * 16));
    }
    __builtin_amdgcn_s_setprio(1);
#pragma unroll
    for (int n = 0; n < 5; ++n) {
      int c = cw * 80 + n * 16 + lrow;
      f16x8 bf = *reinterpret_cast<const f16x8*>(B_ + lk16 * 2560 + ((c ^ (lk16 << 2)) * 16));
      acc[0][n] = __builtin_amdgcn_mfma_f32_16x16x32_f16(ah[0], bf, acc[0][n], 0, 0, 0);
      acc[1][n] = __builtin_amdgcn_mfma_f32_16x16x32_f16(ah[1], bf, acc[1][n], 0, 0, 0);
    }
    __builtin_amdgcn_s_setprio(0);

    if (t < NITER - 1) WRITEI((t + 1) & 1, (t + 1) & 1);
    __syncthreads();
  }
#undef BGLOAD
#undef LOADI
#undef WRITEI

  // ---- result tile to LDS (u f32, t fp16); overwrites staging (post-barrier)
  float* res_u          = reinterpret_cast<float*>(smem);                  // 20480
  unsigned short* res_v = reinterpret_cast<unsigned short*>(smem + 20480); // 10240
#pragma unroll
  for (int m = 0; m < 2; ++m)
#pragma unroll
    for (int n = 0; n < 5; ++n)
#pragma unroll
      for (int rr = 0; rr < 4; ++rr) {
        int row = wr + m * 16 + lk16 * 4 + rr;
        int col = n * 16 + lrow;
        if (cw == 0) res_u[row * 80 + col] = acc[m][n][rr];
        else         res_v[row * 80 + col] = f16b(acc[m][n][rr]);
      }
  __syncthreads();

  // ---- segmented online softmax-pool over this 64-row strip
  int b0 = seg[rs];
  int b1 = seg[rs + RT - 1];
  int nu = (b1 - b0 + 1) * PS;
  for (int u = tid; u < nu; u += 256) {
    int bag = b0 + u / PS;
    int c   = u % PS;
    int sb  = segstart[bag];
    int lo  = max(sb, rs) - rs;
    int hi  = min(segstart[bag + 1], rs + RT) - rs;
    float m_ = -3.4e38f, se = 0.f, st = 0.f;
    for (int r = lo; r < hi; ++r) {
      float v  = res_u[r * 80 + c];
      float tv = f16tof(res_v[r * 80 + c]);
      float nm = fmaxf(m_, v);
      float sc = __expf(m_ - nm);
      float ee = __expf(v - nm);
      se = se * sc + ee;
      st = st * sc + ee * tv;
      m_ = nm;
    }
    int slot = blockIdx.x - (sb >> 6);
    size_t p = ((size_t)bag * NSLOT + slot) * PS + c;
    pm[p] = m_; pse[p] = se; pst[p] = st;
  }
}

// ---------------------------------------------------------------------------
// Kernel 3: merge partial slots per (bag,col) -> zb (= d_out).
// ---------------------------------------------------------------------------
__global__ __launch_bounds__(256) void combine_k(
    const int* __restrict__ segstart,
    const float* __restrict__ pm, const float* __restrict__ pse,
    const float* __restrict__ pst, float* __restrict__ zb) {
  int i = blockIdx.x * 256 + threadIdx.x;   // BB*PS
  if (i >= BB * PS) return;
  int bag = i / PS, c = i % PS;
  int sb = segstart[bag], eb = segstart[bag + 1];
  float z = 0.f;
  if (eb > sb) {
    int ns = ((eb - 1) >> 6) - (sb >> 6) + 1;
    ns = min(ns, NSLOT);
    float m = -3.4e38f, se = 0.f, st = 0.f;
    for (int s = 0; s < ns; ++s) {
      size_t p = ((size_t)bag * NSLOT + s) * PS + c;
      float m2 = pm[p], se2 = pse[p], st2 = pst[p];
      float nm = fmaxf(m, m2);
      float s1 = __expf(m - nm);
      float s2 = __expf(m2 - nm);
      se = se * s1 + se2 * s2;
      st = st * s1 + st2 * s2;
      m = nm;
    }
    z = st / se;
  }
  zb[i] = z;
}

// ---------------------------------------------------------------------------
// Kernel 4: per-column stats + b-scale, IN PLACE on d_out.
// ---------------------------------------------------------------------------
__device__ inline float wave_sum(float v) {
#pragma unroll
  for (int o = 32; o > 0; o >>= 1) v += __shfl_down(v, o, 64);
  return v;
}

__global__ __launch_bounds__(256) void finalize_k(
    const float* __restrict__ bz, float* __restrict__ zb_out) {
  const int c = blockIdx.x;
  const int t = threadIdx.x;

  float bvz = bz[t * PS + c];
  float bsq = bvz * bvz;

  float s = 0.f, ss = 0.f;
  for (int b = t; b < BB; b += 256) {
    float z = zb_out[b * PS + c];
    s += z;
    ss += z * z;
  }

  __shared__ float w0[4], w1[4], w2[4];
  float a0 = wave_sum(bsq);
  float a1 = wave_sum(s);
  float a2 = wave_sum(ss);
  int wid = t >> 6, lane = t & 63;
  if (lane == 0) { w0[wid] = a0; w1[wid] = a1; w2[wid] = a2; }
  __syncthreads();

  __shared__ float sh[3];
  if (t == 0) {
    float B0 = w0[0] + w0[1] + w0[2] + w0[3];
    float S1 = w1[0] + w1[1] + w1[2] + w1[3];
    float S2 = w2[0] + w2[1] + w2[2] + w2[3];
    float bval = sqrtf(B0 / (float)QQ);
    float mean = S1 / (float)BB;
    float var = (S2 - (float)BB * mean * mean) / (float)(BB - 1);
    float sd = sqrtf(fmaxf(var, 0.f));
    if (!(sd > 0.f) || sd != sd) sd = 1.f;
    sh[0] = bval; sh[1] = mean; sh[2] = sd;
  }
  __syncthreads();
  float bval = sh[0], mean = sh[1], sd = sh[2];
  for (int b = t; b < BB; b += 256) {
    zb_out[b * PS + c] = bval * (zb_out[b * PS + c] - mean) / sd;
  }
}

// ---------------------------------------------------------------------------
extern "C" void kernel_launch(void* const* d_in, const int* in_sizes, int n_in,
                              void* d_out, int out_size, void* d_ws, size_t ws_size,
                              hipStream_t stream) {
  const float* x   = (const float*)d_in[0];
  const float* bu  = (const float*)d_in[1];
  const float* bz  = (const float*)d_in[2];
  const int*   seg = (const int*)d_in[3];   // harness narrows int64 -> int32
  float* out = (float*)d_out;

  // workspace layout (bytes):
  //   [0,     16640)  segstart (4097 ints, padded)
  //   [16640, 98560)  bSwz: 8*4*160*8 fp16 = 81920
  //   [98560, ...)    pm / pse / pst: BB*NSLOT*PS floats each
  char* ws = (char*)d_ws;
  int* segstart        = (int*)ws;
  unsigned short* bSwz = (unsigned short*)(ws + 16640);
  size_t pn  = (size_t)BB * NSLOT * PS;
  float* pm  = (float*)(ws + 98560);
  float* pse = pm + pn;
  float* pst = pse + pn;

  bprep_k<<<20, 256, 0, stream>>>(bu, bz, bSwz);
  seg_bounds_k<<<(BB + 1 + 255) / 256, 256, 0, stream>>>(seg, segstart);
  fused_k<<<NN / RT, 256, 0, stream>>>(x, bSwz, seg, segstart, pm, pse, pst);
  combine_k<<<(BB * PS + 255) / 256, 256, 0, stream>>>(segstart, pm, pse, pst, out);
  finalize_k<<<PS, 256, 0, stream>>>(bz, out);
}